// Round 7
// baseline (9564.173 us; speedup 1.0000x reference)
//
#include <hip/hip_runtime.h>

typedef unsigned short u16;
typedef unsigned long long u64;
using bf16x8 = __attribute__((ext_vector_type(8))) short;
using f32x4  = __attribute__((ext_vector_type(4))) float;

#define NBR 8
#define BATCH 32
#define LSEQ 512
#define MROWS (BATCH*LSEQ)   /* 16384 */
#define NPART 32768

__device__ __forceinline__ u16 f2bf(float f) {
  unsigned u = __float_as_uint(f);
  unsigned r = u + 0x7fffu + ((u >> 16) & 1u);
  return (u16)(r >> 16);
}
__device__ __forceinline__ float bf2f(u16 s) {
  return __uint_as_float(((unsigned)s) << 16);
}

// ---------------------------------------------------------------- cvt f32->bf16
__global__ void cvt_kernel(const float* __restrict__ src, u16* __restrict__ dst, int n) {
  int i = blockIdx.x * blockDim.x + threadIdx.x;
  int stride = gridDim.x * blockDim.x;
  for (; i < n; i += stride) dst[i] = f2bf(src[i]);
}

// ---------------------------------------------------------------- FPS (bit-exact vs numpy)
// 8 WGs/batch x 32 batches = 256 WGs. 4 points/thread, coords+dist in VGPRs.
// Round-7: BARRIER-FREE handshake. Each of the 128 waves/batch publishes its
// DPP-reduced max directly (atomicExch, fire-and-forget) into its own slot;
// every wave polls all 128 slots (2 u64 loads/lane) and detects completion by
// a UNIQUE iteration tag in the key low word:
//   key = (bits(d) << 32) | (it << 15) | (0x7FFF - pidx)
// (d>=0; same-it keys order by dist then smallest index == numpy argmax).
// Tag match replaces the nonzero test -> a 2-line ring is race-free (wave
// spread <= 1 handshake since publishing `it` requires detecting `it-1`).
// No __syncthreads in the loop; no LDS; winner resolved in-register by every
// wave (6 xor-shuffles) + broadcast coord load.
__global__ __launch_bounds__(1024) void fps_kernel(const float* __restrict__ xp,
                                                   float* __restrict__ out,
                                                   u64* __restrict__ slots) {
  int w = blockIdx.x;          // WG within batch [0,8)
  int b = blockIdx.y;          // batch
  int tid = threadIdx.x;
  const float* P = xp + (size_t)b * NPART * 3;
  u64* ring = slots + (size_t)b * 256;    // [2][128] u64

  float px[4], py[4], pz[4], dv[4];
#pragma unroll
  for (int k = 0; k < 4; k++) {
    int p = (w << 12) + (k << 10) + tid;
    px[k] = P[3*p]; py[k] = P[3*p+1]; pz[k] = P[3*p+2];
    dv[k] = 1e10f;
  }
  float cx = P[0], cy = P[1], cz = P[2];   // broadcast load, read-only data
  if (w == 0 && tid == 0) {
    float* o = out + ((size_t)b*2048 + 1024) * 3;
    o[0] = cx; o[1] = cy; o[2] = cz;
  }

  int lane = tid & 63, wv = tid >> 6;
  int wavG = (w << 4) | wv;               // global wave id within batch [0,128)

  for (int it = 1; it < 1024; it++) {
    float best = -1.0f; int bk = 0;
#pragma unroll
    for (int k = 0; k < 4; k++) {
      float dx = __fsub_rn(px[k], cx);
      float dy = __fsub_rn(py[k], cy);
      float dz = __fsub_rn(pz[k], cz);
      float d = __fadd_rn(__fadd_rn(__fmul_rn(dx,dx), __fmul_rn(dy,dy)), __fmul_rn(dz,dz));
      float nd = fminf(dv[k], d);
      dv[k] = nd;
      if (nd > best) { best = nd; bk = k; }   // ascending k => first-max per thread
    }
    unsigned pidx = (unsigned)((w << 12) + (bk << 10) + tid);
    u64 pk = ((u64)__float_as_uint(best) << 32)
           | (u64)(((unsigned)it << 15) | (0x7FFFu - pidx));

    // wave64 max via DPP: row_shr 1,2,4,8 then row_bcast15, row_bcast31.
#define DPP_STEP(CTRL) { \
    unsigned lo2 = (unsigned)__builtin_amdgcn_update_dpp(0, (int)(unsigned)(pk & 0xffffffffull), CTRL, 0xF, 0xF, true); \
    unsigned hi2 = (unsigned)__builtin_amdgcn_update_dpp(0, (int)(unsigned)(pk >> 32), CTRL, 0xF, 0xF, true); \
    u64 o = ((u64)hi2 << 32) | lo2; \
    if (o > pk) pk = o; }
    DPP_STEP(0x111) DPP_STEP(0x112) DPP_STEP(0x114) DPP_STEP(0x118)
    DPP_STEP(0x142) DPP_STEP(0x143)
#undef DPP_STEP
    unsigned rlo = (unsigned)__builtin_amdgcn_readlane((int)(unsigned)(pk & 0xffffffffull), 63);
    unsigned rhi = (unsigned)__builtin_amdgcn_readlane((int)(unsigned)(pk >> 32), 63);

    u64* line = ring + (it & 1) * 128;
    if (lane == 0) {
      u64 wmax = ((u64)rhi << 32) | rlo;
      __hip_atomic_exchange(&line[wavG], wmax, __ATOMIC_RELAXED,
                            __HIP_MEMORY_SCOPE_AGENT);   // fire-and-forget
    }

    // poll all 128 slots; tag match == this iteration's value present
    unsigned want = (unsigned)it;
    u64 v0, v1; bool ok;
    do {
      v0 = __hip_atomic_load(&line[lane],      __ATOMIC_RELAXED, __HIP_MEMORY_SCOPE_AGENT);
      v1 = __hip_atomic_load(&line[64 + lane], __ATOMIC_RELAXED, __HIP_MEMORY_SCOPE_AGENT);
      ok = ((((unsigned)v0) >> 15) == want) & ((((unsigned)v1) >> 15) == want);
      if (!__all(ok)) { __builtin_amdgcn_s_sleep(1); ok = false; }
    } while (!ok);

    u64 m = v0 > v1 ? v0 : v1;
#pragma unroll
    for (int off = 1; off < 64; off <<= 1) {
      u64 o = __shfl_xor(m, off);
      if (o > m) m = o;
    }
    unsigned widx = 0x7FFFu - ((unsigned)m & 0x7FFFu);
    const float* pw = P + 3*(size_t)widx;    // same address all lanes: broadcast
    cx = pw[0]; cy = pw[1]; cz = pw[2];
    if (w == 0 && tid == 0) {
      float* o = out + ((size_t)b*2048 + 1024 + it) * 3;
      o[0] = cx; o[1] = cy; o[2] = cz;
    }
  }
}

// ---------------------------------------------------------------- GEMM + fused BN(load)/stats(epilogue)
// C[m,n] = sum_k actA(A[m,k]) * W[n,k]   (both K-major, bf16, fp32 acc)
// actA = bnA ? relu(alpha_k*a + beta_k) : a    (alpha/beta from previous layer's stats)
// epilogue: Y bf16 store + per-channel atomic {sum, sumsq} into statsOut.
__global__ __launch_bounds__(256, 2) void gemm_bn(
    const u16* __restrict__ A, size_t strideA,
    const u16* __restrict__ W, size_t strideW,
    u16* __restrict__ Y, size_t strideY,
    float* __restrict__ statsOut,
    const float* __restrict__ statsIn,
    const float* __restrict__ gam, const float* __restrict__ bet,
    int N, int K, int bnA)
{
  int z = blockIdx.z;
  const u16* Ab = A + (size_t)z * strideA;
  const u16* Wb = W + (size_t)z * strideW;
  u16* Yb = Y + (size_t)z * strideY;
  int m0 = blockIdx.x * 128;
  int n0 = blockIdx.y * 128;

  __shared__ u16 As[128][72];   // +8 pad
  __shared__ u16 Bs[128][72];
  __shared__ float sAl[512];
  __shared__ float sBe[512];

  int tid = threadIdx.x;
  if (bnA) {
    for (int ch = tid; ch < K; ch += 256) {
      float s  = statsIn[(size_t)z*1024 + ch*2];
      float sq = statsIn[(size_t)z*1024 + ch*2 + 1];
      float mean = s * (1.0f/16384.0f);
      float var  = sq * (1.0f/16384.0f) - mean*mean;
      float rs = rsqrtf(var + 1e-5f);
      float al = gam[(size_t)z*K + ch] * rs;
      sAl[ch] = al;
      sBe[ch] = bet[(size_t)z*K + ch] - al*mean;
    }
  }

  f32x4 acc[4][4] = {};
  int lane = tid & 63;
  int wave = tid >> 6;
  int wm = (wave & 1) * 64;
  int wn = (wave >> 1) * 64;
  int lm = lane & 15;
  int lq = lane >> 4;

  for (int k0 = 0; k0 < K; k0 += 64) {
    __syncthreads();
#pragma unroll
    for (int i = 0; i < 4; i++) {
      int f = i*256 + tid;
      int row = f >> 3;
      int kc = (f & 7) * 8;
      uint4 raw = *(const uint4*)(Ab + (size_t)(m0 + row) * K + (k0 + kc));
      if (bnA) {
        u16 us[8]; *(uint4*)us = raw;
        u16 ot[8];
#pragma unroll
        for (int e = 0; e < 8; e++) {
          float v = sAl[k0 + kc + e] * bf2f(us[e]) + sBe[k0 + kc + e];
          ot[e] = f2bf(fmaxf(v, 0.0f));
        }
        *(uint4*)(&As[row][kc]) = *(uint4*)ot;
      } else {
        *(uint4*)(&As[row][kc]) = raw;
      }
    }
#pragma unroll
    for (int i = 0; i < 4; i++) {
      int f = i*256 + tid;
      int row = f >> 3;
      int kc = (f & 7) * 8;
      uint4 v = {0u, 0u, 0u, 0u};
      if (n0 + row < N) v = *(const uint4*)(Wb + (size_t)(n0 + row) * K + (k0 + kc));
      *(uint4*)(&Bs[row][kc]) = v;
    }
    __syncthreads();
#pragma unroll
    for (int kk = 0; kk < 64; kk += 32) {
      bf16x8 af[4], bq[4];
#pragma unroll
      for (int t = 0; t < 4; t++) {
        af[t] = *(const bf16x8*)(&As[wm + t*16 + lm][kk + lq*8]);
        bq[t] = *(const bf16x8*)(&Bs[wn + t*16 + lm][kk + lq*8]);
      }
#pragma unroll
      for (int mt = 0; mt < 4; mt++) {
#pragma unroll
        for (int nt = 0; nt < 4; nt++) {
          acc[mt][nt] = __builtin_amdgcn_mfma_f32_16x16x32_bf16(af[mt], bq[nt], acc[mt][nt], 0, 0, 0);
        }
      }
    }
  }

#pragma unroll
  for (int mt = 0; mt < 4; mt++) {
#pragma unroll
    for (int nt = 0; nt < 4; nt++) {
      int colg = n0 + wn + nt*16 + lm;
      if (colg < N) {
#pragma unroll
        for (int r = 0; r < 4; r++) {
          int rowg = m0 + wm + mt*16 + lq*4 + r;
          Yb[(size_t)rowg * N + colg] = f2bf(acc[mt][nt][r]);
        }
      }
    }
  }
  if (statsOut) {
#pragma unroll
    for (int nt = 0; nt < 4; nt++) {
      float s = 0.f, sq = 0.f;
#pragma unroll
      for (int mt = 0; mt < 4; mt++) {
#pragma unroll
        for (int r = 0; r < 4; r++) { float v = acc[mt][nt][r]; s += v; sq += v*v; }
      }
      s  += __shfl_xor(s, 16);  s  += __shfl_xor(s, 32);
      sq += __shfl_xor(sq, 16); sq += __shfl_xor(sq, 32);
      int colg = n0 + wn + nt*16 + lm;
      if (lq == 0 && colg < N) {
        atomicAdd(&statsOut[(size_t)z*1024 + colg*2],     s);
        atomicAdd(&statsOut[(size_t)z*1024 + colg*2 + 1], sq);
      }
    }
  }
}

// ---------------------------------------------------------------- finale: softmax + pts + 3x64 proj
__global__ __launch_bounds__(256, 1) void finale_kernel(
    const u16* __restrict__ h4,       // [8][16384][64] pre-BN bf16
    const u16* __restrict__ t3,       // [8][16384][128] logits bf16
    const float* __restrict__ stats4,
    const float* __restrict__ mg4, const float* __restrict__ mB4,
    const float* __restrict__ aW4, const float* __restrict__ ab4,
    float* __restrict__ out)
{
  int b = blockIdx.x, g = blockIdx.y;
  int tid = threadIdx.x;
  __shared__ u16 base_s[512*64];
  __shared__ u16 wbuf[512*64];
  __shared__ float ptsb[64*64];
  __shared__ float2 abl[64];
  __shared__ float red[4*64];
  __shared__ float colmax[64];
  __shared__ float colinv[64];

  if (tid < 64) {
    float s  = stats4[(size_t)g*1024 + tid*2];
    float sq = stats4[(size_t)g*1024 + tid*2 + 1];
    float mean = s * (1.0f/16384.0f);
    float var  = sq * (1.0f/16384.0f) - mean*mean;
    float rs = rsqrtf(var + 1e-5f);
    float al = mg4[g*64 + tid] * rs;
    abl[tid] = make_float2(al, mB4[g*64 + tid] - al*mean);
  }
  __syncthreads();

  const u16* h4b = h4 + ((size_t)g*MROWS + b*LSEQ) * 64;
  for (int i = 0; i < 16; i++) {
    int u = i*256 + tid;
    int l = u >> 3;
    int kc = (u & 7) * 8;
    uint4 raw = *(const uint4*)(h4b + (size_t)l*64 + kc);
    u16 us[8]; *(uint4*)us = raw;
    u16 ot[8];
#pragma unroll
    for (int e = 0; e < 8; e++) {
      float2 p = abl[kc + e];
      float v = p.x * bf2f(us[e]) + p.y;
      ot[e] = f2bf(fmaxf(v, 0.0f));
    }
    *(uint4*)(&base_s[l*64 + kc]) = *(uint4*)ot;
  }

  int col = tid & 63;
  int ts  = tid >> 6;
  int mch0 = (tid & 31) * 2;
  int k0 = (tid >> 5) * 8;

  for (int half = 0; half < 2; half++) {
    __syncthreads();
    const u16* t3b = t3 + ((size_t)g*MROWS + b*LSEQ) * 128 + half*64;
    for (int i = 0; i < 16; i++) {
      int u = i*256 + tid;
      int l = u >> 3;
      int kc = (u & 7) * 8;
      *(uint4*)(&wbuf[l*64 + kc]) = *(const uint4*)(t3b + (size_t)l*128 + kc);
    }
    __syncthreads();
    float mx = -1e30f;
    for (int j = 0; j < 128; j++) {
      int l = ts + j*4;
      mx = fmaxf(mx, bf2f(wbuf[l*64 + col]));
    }
    red[ts*64 + col] = mx;
    __syncthreads();
    if (ts == 0)
      colmax[col] = fmaxf(fmaxf(red[col], red[64+col]), fmaxf(red[128+col], red[192+col]));
    __syncthreads();
    mx = colmax[col];
    float sm = 0.0f;
    for (int j = 0; j < 128; j++) {
      int l = ts + j*4;
      float e = __expf(bf2f(wbuf[l*64 + col]) - mx);
      sm += e;
      wbuf[l*64 + col] = f2bf(e);
    }
    red[ts*64 + col] = sm;
    __syncthreads();
    if (ts == 0)
      colinv[col] = 1.0f / (red[col] + red[64+col] + red[128+col] + red[192+col]);
    __syncthreads();

    float a0[8] = {}, a1[8] = {};
    for (int l = 0; l < 512; l++) {
      unsigned wvv = *(const unsigned*)(&wbuf[l*64 + mch0]);
      float w0 = __uint_as_float((wvv & 0xffffu) << 16);
      float w1 = __uint_as_float((wvv >> 16) << 16);
      u16 bs[8]; *(uint4*)bs = *(const uint4*)(&base_s[l*64 + k0]);
#pragma unroll
      for (int e = 0; e < 8; e++) {
        float bv = bf2f(bs[e]);
        a0[e] = fmaf(w0, bv, a0[e]);
        a1[e] = fmaf(w1, bv, a1[e]);
      }
    }
    float i0 = colinv[mch0], i1 = colinv[mch0 + 1];
#pragma unroll
    for (int e = 0; e < 8; e++) {
      ptsb[mch0*64 + k0 + e]       = a0[e] * i0;
      ptsb[(mch0+1)*64 + k0 + e]   = a1[e] * i1;
    }
    __syncthreads();
    if (tid < 64) {
      const float* w4 = aW4 + (size_t)g*192;
      float o0 = ab4[g*3], o1 = ab4[g*3+1], o2 = ab4[g*3+2];
      for (int k = 0; k < 64; k++) {
        float pv = ptsb[tid*64 + k];
        o0 = fmaf(w4[k],      pv, o0);
        o1 = fmaf(w4[64 + k], pv, o1);
        o2 = fmaf(w4[128 + k],pv, o2);
      }
      float* op = out + ((size_t)b*2048 + g*128 + half*64 + tid) * 3;
      op[0] = o0; op[1] = o1; op[2] = o2;
    }
  }
}

// ---------------------------------------------------------------- host
extern "C" void kernel_launch(void* const* d_in, const int* in_sizes, int n_in,
                              void* d_out, int out_size, void* d_ws, size_t ws_size,
                              hipStream_t stream)
{
  (void)in_sizes; (void)n_in; (void)out_size; (void)ws_size;
  const float* x    = (const float*)d_in[0];
  const float* xprt = (const float*)d_in[1];
  const float* mW1 = (const float*)d_in[2];
  const float* mg1 = (const float*)d_in[4];
  const float* mB1 = (const float*)d_in[5];
  const float* mW2 = (const float*)d_in[6];
  const float* mg2 = (const float*)d_in[8];
  const float* mB2 = (const float*)d_in[9];
  const float* mW3 = (const float*)d_in[10];
  const float* mg3 = (const float*)d_in[12];
  const float* mB3 = (const float*)d_in[13];
  const float* mW4 = (const float*)d_in[14];
  const float* mg4 = (const float*)d_in[16];
  const float* mB4 = (const float*)d_in[17];
  const float* aW1 = (const float*)d_in[18];
  const float* ag1 = (const float*)d_in[20];
  const float* aB1 = (const float*)d_in[21];
  const float* aW2 = (const float*)d_in[22];
  const float* ag2 = (const float*)d_in[24];
  const float* aB2 = (const float*)d_in[25];
  const float* aW3 = (const float*)d_in[26];
  const float* aW4 = (const float*)d_in[28];
  const float* ab4 = (const float*)d_in[29];
  float* out = (float*)d_out;

  char* ws = (char*)d_ws;
  size_t off = 0;
  auto carve = [&](size_t bytes) -> char* {
    char* p = ws + off;
    off += (bytes + 255) & ~(size_t)255;
    return p;
  };
  u16* xb   = (u16*)carve((size_t)MROWS*256*2);
  u16* w1b  = (u16*)carve((size_t)NBR*512*256*2);
  u16* w2b  = (u16*)carve((size_t)NBR*512*512*2);
  u16* w3b  = (u16*)carve((size_t)NBR*512*512*2);
  u16* w4b  = (u16*)carve((size_t)NBR*64*512*2);
  u16* aw1b = (u16*)carve((size_t)NBR*64*64*2);
  u16* aw2b = (u16*)carve((size_t)NBR*128*64*2);
  u16* aw3b = (u16*)carve((size_t)NBR*128*128*2);
  u16* hA   = (u16*)carve((size_t)2*MROWS*512*2);
  u16* hB   = (u16*)carve((size_t)2*MROWS*512*2);
  u16* h4   = (u16*)carve((size_t)NBR*MROWS*64*2);
  u16* t1   = (u16*)carve((size_t)NBR*MROWS*64*2);
  float* stats = (float*)carve((size_t)6*NBR*1024*4);
  u64* slots = (u64*)carve((size_t)BATCH*256*8);    // [batch][2 ring][128 waves]
  u16* t2 = hB;
  u16* t3 = hA;

  cvt_kernel<<<1024, 256, 0, stream>>>(x,   xb,   MROWS*256);
  cvt_kernel<<<1024, 256, 0, stream>>>(mW1, w1b,  NBR*512*256);
  cvt_kernel<<<1024, 256, 0, stream>>>(mW2, w2b,  NBR*512*512);
  cvt_kernel<<<1024, 256, 0, stream>>>(mW3, w3b,  NBR*512*512);
  cvt_kernel<<<1024, 256, 0, stream>>>(mW4, w4b,  NBR*64*512);
  cvt_kernel<<<256,  256, 0, stream>>>(aW1, aw1b, NBR*64*64);
  cvt_kernel<<<256,  256, 0, stream>>>(aW2, aw2b, NBR*128*64);
  cvt_kernel<<<256,  256, 0, stream>>>(aW3, aw3b, NBR*128*128);
  hipMemsetAsync(stats, 0, (size_t)6*NBR*1024*4, stream);
  hipMemsetAsync(slots, 0, (size_t)BATCH*256*8, stream);

  fps_kernel<<<dim3(8, BATCH), 1024, 0, stream>>>(xprt, out, slots);

  for (int p = 0; p < 4; p++) {
    size_t g0 = (size_t)p * 2;
    gemm_bn<<<dim3(128,4,2), 256, 0, stream>>>(
      xb, (size_t)0, w1b + g0*512*256, (size_t)512*256,
      hA, (size_t)MROWS*512,
      stats + 0*NBR*1024 + g0*1024,
      (const float*)nullptr, (const float*)nullptr, (const float*)nullptr,
      512, 256, 0);
    gemm_bn<<<dim3(128,4,2), 256, 0, stream>>>(
      hA, (size_t)MROWS*512, w2b + g0*512*512, (size_t)512*512,
      hB, (size_t)MROWS*512,
      stats + 1*NBR*1024 + g0*1024,
      stats + 0*NBR*1024 + g0*1024, mg1 + g0*512, mB1 + g0*512,
      512, 512, 1);
    gemm_bn<<<dim3(128,4,2), 256, 0, stream>>>(
      hB, (size_t)MROWS*512, w3b + g0*512*512, (size_t)512*512,
      hA, (size_t)MROWS*512,
      stats + 2*NBR*1024 + g0*1024,
      stats + 1*NBR*1024 + g0*1024, mg2 + g0*512, mB2 + g0*512,
      512, 512, 1);
    gemm_bn<<<dim3(128,1,2), 256, 0, stream>>>(
      hA, (size_t)MROWS*512, w4b + g0*64*512, (size_t)64*512,
      h4 + g0*MROWS*64, (size_t)MROWS*64,
      stats + 3*NBR*1024 + g0*1024,
      stats + 2*NBR*1024 + g0*1024, mg3 + g0*512, mB3 + g0*512,
      64, 512, 1);
  }

  gemm_bn<<<dim3(128,1,8), 256, 0, stream>>>(
    h4, (size_t)MROWS*64, aw1b, (size_t)64*64,
    t1, (size_t)MROWS*64,
    stats + 4*NBR*1024,
    stats + 3*NBR*1024, mg4, mB4,
    64, 64, 1);
  gemm_bn<<<dim3(128,1,8), 256, 0, stream>>>(
    t1, (size_t)MROWS*64, aw2b, (size_t)128*64,
    t2, (size_t)MROWS*128,
    stats + 5*NBR*1024,
    stats + 4*NBR*1024, ag1, aB1,
    128, 64, 1);
  gemm_bn<<<dim3(128,1,8), 256, 0, stream>>>(
    t2, (size_t)MROWS*128, aw3b, (size_t)128*128,
    t3, (size_t)MROWS*128,
    (float*)nullptr,
    stats + 5*NBR*1024, ag2, aB2,
    128, 128, 1);

  finale_kernel<<<dim3(32,8), 256, 0, stream>>>(
    h4, t3, stats + 3*NBR*1024, mg4, mB4, aW4, ab4, out);
}

// Round 8
// 3443.682 us; speedup vs baseline: 2.7773x; 2.7773x over previous
//
#include <hip/hip_runtime.h>

typedef unsigned short u16;
typedef unsigned long long u64;
using bf16x8 = __attribute__((ext_vector_type(8))) short;
using f32x4  = __attribute__((ext_vector_type(4))) float;

#define NBR 8
#define BATCH 32
#define LSEQ 512
#define MROWS (BATCH*LSEQ)   /* 16384 */
#define NPART 32768

__device__ __forceinline__ u16 f2bf(float f) {
  unsigned u = __float_as_uint(f);
  unsigned r = u + 0x7fffu + ((u >> 16) & 1u);
  return (u16)(r >> 16);
}
__device__ __forceinline__ float bf2f(u16 s) {
  return __uint_as_float(((unsigned)s) << 16);
}

// ---------------------------------------------------------------- cvt f32->bf16
__global__ void cvt_kernel(const float* __restrict__ src, u16* __restrict__ dst, int n) {
  int i = blockIdx.x * blockDim.x + threadIdx.x;
  int stride = gridDim.x * blockDim.x;
  for (; i < n; i += stride) dst[i] = f2bf(src[i]);
}

// ---------------------------------------------------------------- FPS (bit-exact vs numpy)
// 8 WGs/batch x 32 batches = 256 WGs. 4 points/thread, coords+dist in VGPRs.
// Key: (bits(d)<<32) | (0xFFFFFFFF - idx); u64 max == numpy first-index argmax.
// Publication (R6, proven): per-WG LDS funnel -> wave0 single atomicExch into
// slot[it*8+w] -- the 8 slots of an iteration are ONE 64B cacheline.
// Polling (R8): ALL 16 waves poll that one line directly (lane -> slot[lane&7],
// 64 lanes in one line = 1 fabric request per wave-poll). Removes the 2nd
// barrier + LDS cb broadcast from R6's critical path. R7 post-mortem: poll
// cohort x poll FOOTPRINT must stay ~1 line/wave (128-slot poll = 16 lines =
// 1GB refetch + 4x regression).
// XCD swizzle: all 8 WGs of a batch share lin%8 -> same XCD (heuristic,
// correctness-free): batch's slot line + P data localize in that XCD's L2.
__global__ __launch_bounds__(1024) void fps_kernel(const float* __restrict__ xp,
                                                   float* __restrict__ out,
                                                   u64* __restrict__ slots) {
  int lin = blockIdx.x + (blockIdx.y << 3);
  int xcd = lin & 7, ix = lin >> 3;
  int b = ((ix & 3) << 3) | xcd;   // batch [0,32)
  int w = ix >> 2;                 // WG within batch [0,8)
  int tid = threadIdx.x;
  const float* P = xp + (size_t)b * NPART * 3;
  u64* slot = slots + (size_t)b * 8192;   // [1024 iters][8 WGs], 64B/iter

  __shared__ u64 part[16];

  float px[4], py[4], pz[4], dv[4];
#pragma unroll
  for (int k = 0; k < 4; k++) {
    int p = (w << 12) + (k << 10) + tid;
    px[k] = P[3*p]; py[k] = P[3*p+1]; pz[k] = P[3*p+2];
    dv[k] = 1e10f;
  }
  float cx = P[0], cy = P[1], cz = P[2];   // broadcast load, read-only data
  if (w == 0 && tid == 0) {
    float* o = out + ((size_t)b*2048 + 1024) * 3;
    o[0] = cx; o[1] = cy; o[2] = cz;
  }

  int lane = tid & 63, wv = tid >> 6;
  for (int it = 1; it < 1024; it++) {
    float best = -1.0f; int bk = 0;
#pragma unroll
    for (int k = 0; k < 4; k++) {
      float dx = __fsub_rn(px[k], cx);
      float dy = __fsub_rn(py[k], cy);
      float dz = __fsub_rn(pz[k], cz);
      float d = __fadd_rn(__fadd_rn(__fmul_rn(dx,dx), __fmul_rn(dy,dy)), __fmul_rn(dz,dz));
      float nd = fminf(dv[k], d);
      dv[k] = nd;
      if (nd > best) { best = nd; bk = k; }   // ascending k => first-max per thread
    }
    unsigned pidx = (unsigned)((w << 12) + (bk << 10) + tid);
    u64 pk = ((u64)__float_as_uint(best) << 32) | (u64)(0xFFFFFFFFu - pidx);

    // wave64 max via DPP: row_shr 1,2,4,8 then row_bcast15, row_bcast31.
#define DPP_STEP(CTRL) { \
    unsigned lo2 = (unsigned)__builtin_amdgcn_update_dpp(0, (int)(unsigned)(pk & 0xffffffffull), CTRL, 0xF, 0xF, true); \
    unsigned hi2 = (unsigned)__builtin_amdgcn_update_dpp(0, (int)(unsigned)(pk >> 32), CTRL, 0xF, 0xF, true); \
    u64 o = ((u64)hi2 << 32) | lo2; \
    if (o > pk) pk = o; }
    DPP_STEP(0x111) DPP_STEP(0x112) DPP_STEP(0x114) DPP_STEP(0x118)
    DPP_STEP(0x142) DPP_STEP(0x143)
#undef DPP_STEP
    unsigned rlo = (unsigned)__builtin_amdgcn_readlane((int)(unsigned)(pk & 0xffffffffull), 63);
    unsigned rhi = (unsigned)__builtin_amdgcn_readlane((int)(unsigned)(pk >> 32), 63);
    if (lane == 0) part[wv] = ((u64)rhi << 32) | rlo;
    __syncthreads();   // funnel barrier (the ONLY barrier in the loop)

    if (wv == 0) {     // wave 0: reduce 16 partials, publish WG max
      u64 pv = part[lane & 15];
#pragma unroll
      for (int off = 1; off < 16; off <<= 1) {
        u64 o = __shfl_xor(pv, off);
        if (o > pv) pv = o;
      }
      if (lane == 0) {
        __hip_atomic_exchange(&slot[it*8 + w], pv, __ATOMIC_RELAXED,
                              __HIP_MEMORY_SCOPE_AGENT);   // fire-and-forget
      }
    }

    // every wave polls the iteration's single 8-slot cacheline
    u64 v; bool ok;
    do {
      v = __hip_atomic_load(&slot[it*8 + (lane & 7)], __ATOMIC_RELAXED,
                            __HIP_MEMORY_SCOPE_AGENT);
      ok = (v != 0);   // key low word >= 0xFFFF8000, never 0
      if (!__all(ok)) { __builtin_amdgcn_s_sleep(1); ok = false; }
    } while (!ok);
#pragma unroll
    for (int off = 1; off < 8; off <<= 1) {
      u64 o = __shfl_xor(v, off);
      if (o > v) v = o;
    }
    unsigned widx = 0xFFFFFFFFu - (unsigned)(v & 0xFFFFFFFFull);
    const float* pw = P + 3*(size_t)widx;    // same address all lanes: broadcast
    cx = pw[0]; cy = pw[1]; cz = pw[2];
    if (w == 0 && tid == 0) {
      float* o = out + ((size_t)b*2048 + 1024 + it) * 3;
      o[0] = cx; o[1] = cy; o[2] = cz;
    }
  }
}

// ---------------------------------------------------------------- GEMM + fused BN(load)/stats(epilogue)
// C[m,n] = sum_k actA(A[m,k]) * W[n,k]   (both K-major, bf16, fp32 acc)
// actA = bnA ? relu(alpha_k*a + beta_k) : a    (alpha/beta from previous layer's stats)
// epilogue: Y bf16 store + per-channel atomic {sum, sumsq} into statsOut.
__global__ __launch_bounds__(256, 2) void gemm_bn(
    const u16* __restrict__ A, size_t strideA,
    const u16* __restrict__ W, size_t strideW,
    u16* __restrict__ Y, size_t strideY,
    float* __restrict__ statsOut,
    const float* __restrict__ statsIn,
    const float* __restrict__ gam, const float* __restrict__ bet,
    int N, int K, int bnA)
{
  int z = blockIdx.z;
  const u16* Ab = A + (size_t)z * strideA;
  const u16* Wb = W + (size_t)z * strideW;
  u16* Yb = Y + (size_t)z * strideY;
  int m0 = blockIdx.x * 128;
  int n0 = blockIdx.y * 128;

  __shared__ u16 As[128][72];   // +8 pad
  __shared__ u16 Bs[128][72];
  __shared__ float sAl[512];
  __shared__ float sBe[512];

  int tid = threadIdx.x;
  if (bnA) {
    for (int ch = tid; ch < K; ch += 256) {
      float s  = statsIn[(size_t)z*1024 + ch*2];
      float sq = statsIn[(size_t)z*1024 + ch*2 + 1];
      float mean = s * (1.0f/16384.0f);
      float var  = sq * (1.0f/16384.0f) - mean*mean;
      float rs = rsqrtf(var + 1e-5f);
      float al = gam[(size_t)z*K + ch] * rs;
      sAl[ch] = al;
      sBe[ch] = bet[(size_t)z*K + ch] - al*mean;
    }
  }

  f32x4 acc[4][4] = {};
  int lane = tid & 63;
  int wave = tid >> 6;
  int wm = (wave & 1) * 64;
  int wn = (wave >> 1) * 64;
  int lm = lane & 15;
  int lq = lane >> 4;

  for (int k0 = 0; k0 < K; k0 += 64) {
    __syncthreads();
#pragma unroll
    for (int i = 0; i < 4; i++) {
      int f = i*256 + tid;
      int row = f >> 3;
      int kc = (f & 7) * 8;
      uint4 raw = *(const uint4*)(Ab + (size_t)(m0 + row) * K + (k0 + kc));
      if (bnA) {
        u16 us[8]; *(uint4*)us = raw;
        u16 ot[8];
#pragma unroll
        for (int e = 0; e < 8; e++) {
          float v = sAl[k0 + kc + e] * bf2f(us[e]) + sBe[k0 + kc + e];
          ot[e] = f2bf(fmaxf(v, 0.0f));
        }
        *(uint4*)(&As[row][kc]) = *(uint4*)ot;
      } else {
        *(uint4*)(&As[row][kc]) = raw;
      }
    }
#pragma unroll
    for (int i = 0; i < 4; i++) {
      int f = i*256 + tid;
      int row = f >> 3;
      int kc = (f & 7) * 8;
      uint4 v = {0u, 0u, 0u, 0u};
      if (n0 + row < N) v = *(const uint4*)(Wb + (size_t)(n0 + row) * K + (k0 + kc));
      *(uint4*)(&Bs[row][kc]) = v;
    }
    __syncthreads();
#pragma unroll
    for (int kk = 0; kk < 64; kk += 32) {
      bf16x8 af[4], bq[4];
#pragma unroll
      for (int t = 0; t < 4; t++) {
        af[t] = *(const bf16x8*)(&As[wm + t*16 + lm][kk + lq*8]);
        bq[t] = *(const bf16x8*)(&Bs[wn + t*16 + lm][kk + lq*8]);
      }
#pragma unroll
      for (int mt = 0; mt < 4; mt++) {
#pragma unroll
        for (int nt = 0; nt < 4; nt++) {
          acc[mt][nt] = __builtin_amdgcn_mfma_f32_16x16x32_bf16(af[mt], bq[nt], acc[mt][nt], 0, 0, 0);
        }
      }
    }
  }

#pragma unroll
  for (int mt = 0; mt < 4; mt++) {
#pragma unroll
    for (int nt = 0; nt < 4; nt++) {
      int colg = n0 + wn + nt*16 + lm;
      if (colg < N) {
#pragma unroll
        for (int r = 0; r < 4; r++) {
          int rowg = m0 + wm + mt*16 + lq*4 + r;
          Yb[(size_t)rowg * N + colg] = f2bf(acc[mt][nt][r]);
        }
      }
    }
  }
  if (statsOut) {
#pragma unroll
    for (int nt = 0; nt < 4; nt++) {
      float s = 0.f, sq = 0.f;
#pragma unroll
      for (int mt = 0; mt < 4; mt++) {
#pragma unroll
        for (int r = 0; r < 4; r++) { float v = acc[mt][nt][r]; s += v; sq += v*v; }
      }
      s  += __shfl_xor(s, 16);  s  += __shfl_xor(s, 32);
      sq += __shfl_xor(sq, 16); sq += __shfl_xor(sq, 32);
      int colg = n0 + wn + nt*16 + lm;
      if (lq == 0 && colg < N) {
        atomicAdd(&statsOut[(size_t)z*1024 + colg*2],     s);
        atomicAdd(&statsOut[(size_t)z*1024 + colg*2 + 1], sq);
      }
    }
  }
}

// ---------------------------------------------------------------- finale: softmax + pts + 3x64 proj
__global__ __launch_bounds__(256, 1) void finale_kernel(
    const u16* __restrict__ h4,       // [8][16384][64] pre-BN bf16
    const u16* __restrict__ t3,       // [8][16384][128] logits bf16
    const float* __restrict__ stats4,
    const float* __restrict__ mg4, const float* __restrict__ mB4,
    const float* __restrict__ aW4, const float* __restrict__ ab4,
    float* __restrict__ out)
{
  int b = blockIdx.x, g = blockIdx.y;
  int tid = threadIdx.x;
  __shared__ u16 base_s[512*64];
  __shared__ u16 wbuf[512*64];
  __shared__ float ptsb[64*64];
  __shared__ float2 abl[64];
  __shared__ float red[4*64];
  __shared__ float colmax[64];
  __shared__ float colinv[64];

  if (tid < 64) {
    float s  = stats4[(size_t)g*1024 + tid*2];
    float sq = stats4[(size_t)g*1024 + tid*2 + 1];
    float mean = s * (1.0f/16384.0f);
    float var  = sq * (1.0f/16384.0f) - mean*mean;
    float rs = rsqrtf(var + 1e-5f);
    float al = mg4[g*64 + tid] * rs;
    abl[tid] = make_float2(al, mB4[g*64 + tid] - al*mean);
  }
  __syncthreads();

  const u16* h4b = h4 + ((size_t)g*MROWS + b*LSEQ) * 64;
  for (int i = 0; i < 16; i++) {
    int u = i*256 + tid;
    int l = u >> 3;
    int kc = (u & 7) * 8;
    uint4 raw = *(const uint4*)(h4b + (size_t)l*64 + kc);
    u16 us[8]; *(uint4*)us = raw;
    u16 ot[8];
#pragma unroll
    for (int e = 0; e < 8; e++) {
      float2 p = abl[kc + e];
      float v = p.x * bf2f(us[e]) + p.y;
      ot[e] = f2bf(fmaxf(v, 0.0f));
    }
    *(uint4*)(&base_s[l*64 + kc]) = *(uint4*)ot;
  }

  int col = tid & 63;
  int ts  = tid >> 6;
  int mch0 = (tid & 31) * 2;
  int k0 = (tid >> 5) * 8;

  for (int half = 0; half < 2; half++) {
    __syncthreads();
    const u16* t3b = t3 + ((size_t)g*MROWS + b*LSEQ) * 128 + half*64;
    for (int i = 0; i < 16; i++) {
      int u = i*256 + tid;
      int l = u >> 3;
      int kc = (u & 7) * 8;
      *(uint4*)(&wbuf[l*64 + kc]) = *(const uint4*)(t3b + (size_t)l*128 + kc);
    }
    __syncthreads();
    float mx = -1e30f;
    for (int j = 0; j < 128; j++) {
      int l = ts + j*4;
      mx = fmaxf(mx, bf2f(wbuf[l*64 + col]));
    }
    red[ts*64 + col] = mx;
    __syncthreads();
    if (ts == 0)
      colmax[col] = fmaxf(fmaxf(red[col], red[64+col]), fmaxf(red[128+col], red[192+col]));
    __syncthreads();
    mx = colmax[col];
    float sm = 0.0f;
    for (int j = 0; j < 128; j++) {
      int l = ts + j*4;
      float e = __expf(bf2f(wbuf[l*64 + col]) - mx);
      sm += e;
      wbuf[l*64 + col] = f2bf(e);
    }
    red[ts*64 + col] = sm;
    __syncthreads();
    if (ts == 0)
      colinv[col] = 1.0f / (red[col] + red[64+col] + red[128+col] + red[192+col]);
    __syncthreads();

    float a0[8] = {}, a1[8] = {};
    for (int l = 0; l < 512; l++) {
      unsigned wvv = *(const unsigned*)(&wbuf[l*64 + mch0]);
      float w0 = __uint_as_float((wvv & 0xffffu) << 16);
      float w1 = __uint_as_float((wvv >> 16) << 16);
      u16 bs[8]; *(uint4*)bs = *(const uint4*)(&base_s[l*64 + k0]);
#pragma unroll
      for (int e = 0; e < 8; e++) {
        float bv = bf2f(bs[e]);
        a0[e] = fmaf(w0, bv, a0[e]);
        a1[e] = fmaf(w1, bv, a1[e]);
      }
    }
    float i0 = colinv[mch0], i1 = colinv[mch0 + 1];
#pragma unroll
    for (int e = 0; e < 8; e++) {
      ptsb[mch0*64 + k0 + e]       = a0[e] * i0;
      ptsb[(mch0+1)*64 + k0 + e]   = a1[e] * i1;
    }
    __syncthreads();
    if (tid < 64) {
      const float* w4 = aW4 + (size_t)g*192;
      float o0 = ab4[g*3], o1 = ab4[g*3+1], o2 = ab4[g*3+2];
      for (int k = 0; k < 64; k++) {
        float pv = ptsb[tid*64 + k];
        o0 = fmaf(w4[k],      pv, o0);
        o1 = fmaf(w4[64 + k], pv, o1);
        o2 = fmaf(w4[128 + k],pv, o2);
      }
      float* op = out + ((size_t)b*2048 + g*128 + half*64 + tid) * 3;
      op[0] = o0; op[1] = o1; op[2] = o2;
    }
  }
}

// ---------------------------------------------------------------- host
extern "C" void kernel_launch(void* const* d_in, const int* in_sizes, int n_in,
                              void* d_out, int out_size, void* d_ws, size_t ws_size,
                              hipStream_t stream)
{
  (void)in_sizes; (void)n_in; (void)out_size; (void)ws_size;
  const float* x    = (const float*)d_in[0];
  const float* xprt = (const float*)d_in[1];
  const float* mW1 = (const float*)d_in[2];
  const float* mg1 = (const float*)d_in[4];
  const float* mB1 = (const float*)d_in[5];
  const float* mW2 = (const float*)d_in[6];
  const float* mg2 = (const float*)d_in[8];
  const float* mB2 = (const float*)d_in[9];
  const float* mW3 = (const float*)d_in[10];
  const float* mg3 = (const float*)d_in[12];
  const float* mB3 = (const float*)d_in[13];
  const float* mW4 = (const float*)d_in[14];
  const float* mg4 = (const float*)d_in[16];
  const float* mB4 = (const float*)d_in[17];
  const float* aW1 = (const float*)d_in[18];
  const float* ag1 = (const float*)d_in[20];
  const float* aB1 = (const float*)d_in[21];
  const float* aW2 = (const float*)d_in[22];
  const float* ag2 = (const float*)d_in[24];
  const float* aB2 = (const float*)d_in[25];
  const float* aW3 = (const float*)d_in[26];
  const float* aW4 = (const float*)d_in[28];
  const float* ab4 = (const float*)d_in[29];
  float* out = (float*)d_out;

  char* ws = (char*)d_ws;
  size_t off = 0;
  auto carve = [&](size_t bytes) -> char* {
    char* p = ws + off;
    off += (bytes + 255) & ~(size_t)255;
    return p;
  };
  u16* xb   = (u16*)carve((size_t)MROWS*256*2);
  u16* w1b  = (u16*)carve((size_t)NBR*512*256*2);
  u16* w2b  = (u16*)carve((size_t)NBR*512*512*2);
  u16* w3b  = (u16*)carve((size_t)NBR*512*512*2);
  u16* w4b  = (u16*)carve((size_t)NBR*64*512*2);
  u16* aw1b = (u16*)carve((size_t)NBR*64*64*2);
  u16* aw2b = (u16*)carve((size_t)NBR*128*64*2);
  u16* aw3b = (u16*)carve((size_t)NBR*128*128*2);
  u16* hA   = (u16*)carve((size_t)2*MROWS*512*2);
  u16* hB   = (u16*)carve((size_t)2*MROWS*512*2);
  u16* h4   = (u16*)carve((size_t)NBR*MROWS*64*2);
  u16* t1   = (u16*)carve((size_t)NBR*MROWS*64*2);
  float* stats = (float*)carve((size_t)6*NBR*1024*4);
  u64* slots = (u64*)carve((size_t)BATCH*8192*8);   // [batch][1024 iters][8 WGs]
  u16* t2 = hB;
  u16* t3 = hA;

  cvt_kernel<<<1024, 256, 0, stream>>>(x,   xb,   MROWS*256);
  cvt_kernel<<<1024, 256, 0, stream>>>(mW1, w1b,  NBR*512*256);
  cvt_kernel<<<1024, 256, 0, stream>>>(mW2, w2b,  NBR*512*512);
  cvt_kernel<<<1024, 256, 0, stream>>>(mW3, w3b,  NBR*512*512);
  cvt_kernel<<<1024, 256, 0, stream>>>(mW4, w4b,  NBR*64*512);
  cvt_kernel<<<256,  256, 0, stream>>>(aW1, aw1b, NBR*64*64);
  cvt_kernel<<<256,  256, 0, stream>>>(aW2, aw2b, NBR*128*64);
  cvt_kernel<<<256,  256, 0, stream>>>(aW3, aw3b, NBR*128*128);
  hipMemsetAsync(stats, 0, (size_t)6*NBR*1024*4, stream);
  hipMemsetAsync(slots, 0, (size_t)BATCH*8192*8, stream);

  fps_kernel<<<dim3(8, BATCH), 1024, 0, stream>>>(xprt, out, slots);

  for (int p = 0; p < 4; p++) {
    size_t g0 = (size_t)p * 2;
    gemm_bn<<<dim3(128,4,2), 256, 0, stream>>>(
      xb, (size_t)0, w1b + g0*512*256, (size_t)512*256,
      hA, (size_t)MROWS*512,
      stats + 0*NBR*1024 + g0*1024,
      (const float*)nullptr, (const float*)nullptr, (const float*)nullptr,
      512, 256, 0);
    gemm_bn<<<dim3(128,4,2), 256, 0, stream>>>(
      hA, (size_t)MROWS*512, w2b + g0*512*512, (size_t)512*512,
      hB, (size_t)MROWS*512,
      stats + 1*NBR*1024 + g0*1024,
      stats + 0*NBR*1024 + g0*1024, mg1 + g0*512, mB1 + g0*512,
      512, 512, 1);
    gemm_bn<<<dim3(128,4,2), 256, 0, stream>>>(
      hB, (size_t)MROWS*512, w3b + g0*512*512, (size_t)512*512,
      hA, (size_t)MROWS*512,
      stats + 2*NBR*1024 + g0*1024,
      stats + 1*NBR*1024 + g0*1024, mg2 + g0*512, mB2 + g0*512,
      512, 512, 1);
    gemm_bn<<<dim3(128,1,2), 256, 0, stream>>>(
      hA, (size_t)MROWS*512, w4b + g0*64*512, (size_t)64*512,
      h4 + g0*MROWS*64, (size_t)MROWS*64,
      stats + 3*NBR*1024 + g0*1024,
      stats + 2*NBR*1024 + g0*1024, mg3 + g0*512, mB3 + g0*512,
      64, 512, 1);
  }

  gemm_bn<<<dim3(128,1,8), 256, 0, stream>>>(
    h4, (size_t)MROWS*64, aw1b, (size_t)64*64,
    t1, (size_t)MROWS*64,
    stats + 4*NBR*1024,
    stats + 3*NBR*1024, mg4, mB4,
    64, 64, 1);
  gemm_bn<<<dim3(128,1,8), 256, 0, stream>>>(
    t1, (size_t)MROWS*64, aw2b, (size_t)128*64,
    t2, (size_t)MROWS*128,
    stats + 5*NBR*1024,
    stats + 4*NBR*1024, ag1, aB1,
    128, 64, 1);
  gemm_bn<<<dim3(128,1,8), 256, 0, stream>>>(
    t2, (size_t)MROWS*128, aw3b, (size_t)128*128,
    t3, (size_t)MROWS*128,
    (float*)nullptr,
    stats + 5*NBR*1024, ag2, aB2,
    128, 128, 1);

  finale_kernel<<<dim3(32,8), 256, 0, stream>>>(
    h4, t3, stats + 3*NBR*1024, mg4, mB4, aW4, ab4, out);
}

// Round 9
// 2989.016 us; speedup vs baseline: 3.1998x; 1.1521x over previous
//
#include <hip/hip_runtime.h>

typedef unsigned short u16;
typedef unsigned long long u64;
using bf16x8 = __attribute__((ext_vector_type(8))) short;
using f32x4  = __attribute__((ext_vector_type(4))) float;

#define NBR 8
#define BATCH 32
#define LSEQ 512
#define MROWS (BATCH*LSEQ)   /* 16384 */
#define NPART 32768

__device__ __forceinline__ u16 f2bf(float f) {
  unsigned u = __float_as_uint(f);
  unsigned r = u + 0x7fffu + ((u >> 16) & 1u);
  return (u16)(r >> 16);
}
__device__ __forceinline__ float bf2f(u16 s) {
  return __uint_as_float(((unsigned)s) << 16);
}

// ---------------------------------------------------------------- cvt f32->bf16
__global__ void cvt_kernel(const float* __restrict__ src, u16* __restrict__ dst, int n) {
  int i = blockIdx.x * blockDim.x + threadIdx.x;
  int stride = gridDim.x * blockDim.x;
  for (; i < n; i += stride) dst[i] = f2bf(src[i]);
}

// ---------------------------------------------------------------- FPS (bit-exact vs numpy) — R6 verbatim (proven 1.92ms)
__global__ __launch_bounds__(1024) void fps_kernel(const float* __restrict__ xp,
                                                   float* __restrict__ out,
                                                   u64* __restrict__ slots) {
  int w = blockIdx.x;          // WG within batch [0,8)
  int b = blockIdx.y;          // batch
  int tid = threadIdx.x;
  const float* P = xp + (size_t)b * NPART * 3;
  u64* slot = slots + (size_t)b * 8192;   // [1024 iters][8 WGs], 64B/iter

  __shared__ u64 part[16];
  __shared__ float cb[3];

  float px[4], py[4], pz[4], dv[4];
#pragma unroll
  for (int k = 0; k < 4; k++) {
    int p = (w << 12) + (k << 10) + tid;
    px[k] = P[3*p]; py[k] = P[3*p+1]; pz[k] = P[3*p+2];
    dv[k] = 1e10f;
  }
  float cx = P[0], cy = P[1], cz = P[2];
  if (w == 0 && tid == 0) {
    float* o = out + ((size_t)b*2048 + 1024) * 3;
    o[0] = cx; o[1] = cy; o[2] = cz;
  }

  int lane = tid & 63, wv = tid >> 6;
  for (int it = 1; it < 1024; it++) {
    float best = -1.0f; int bk = 0;
#pragma unroll
    for (int k = 0; k < 4; k++) {
      float dx = __fsub_rn(px[k], cx);
      float dy = __fsub_rn(py[k], cy);
      float dz = __fsub_rn(pz[k], cz);
      float d = __fadd_rn(__fadd_rn(__fmul_rn(dx,dx), __fmul_rn(dy,dy)), __fmul_rn(dz,dz));
      float nd = fminf(dv[k], d);
      dv[k] = nd;
      if (nd > best) { best = nd; bk = k; }
    }
    unsigned pidx = (unsigned)((w << 12) + (bk << 10) + tid);
    u64 pk = ((u64)__float_as_uint(best) << 32) | (u64)(0xFFFFFFFFu - pidx);

#define DPP_STEP(CTRL) { \
    unsigned lo2 = (unsigned)__builtin_amdgcn_update_dpp(0, (int)(unsigned)(pk & 0xffffffffull), CTRL, 0xF, 0xF, true); \
    unsigned hi2 = (unsigned)__builtin_amdgcn_update_dpp(0, (int)(unsigned)(pk >> 32), CTRL, 0xF, 0xF, true); \
    u64 o = ((u64)hi2 << 32) | lo2; \
    if (o > pk) pk = o; }
    DPP_STEP(0x111) DPP_STEP(0x112) DPP_STEP(0x114) DPP_STEP(0x118)
    DPP_STEP(0x142) DPP_STEP(0x143)
#undef DPP_STEP
    unsigned rlo = (unsigned)__builtin_amdgcn_readlane((int)(unsigned)(pk & 0xffffffffull), 63);
    unsigned rhi = (unsigned)__builtin_amdgcn_readlane((int)(unsigned)(pk >> 32), 63);
    if (lane == 0) part[wv] = ((u64)rhi << 32) | rlo;
    __syncthreads();

    if (wv == 0) {   // wave 0 only: publish + poll + resolve
      u64 pv = part[lane & 15];
#pragma unroll
      for (int off = 1; off < 16; off <<= 1) {
        u64 o = __shfl_xor(pv, off);
        if (o > pv) pv = o;
      }
      if (lane == 0) {
        atomicExch(&slot[it*8 + w], pv);   // device-scope, fire-and-forget
      }
      u64 v;
      do {
        v = __hip_atomic_load(&slot[it*8 + (lane & 7)], __ATOMIC_RELAXED,
                              __HIP_MEMORY_SCOPE_AGENT);
      } while (!__all(v != 0));            // key low word >= 0xFFFF8000, never 0
#pragma unroll
      for (int off = 1; off < 8; off <<= 1) {
        u64 o = __shfl_xor(v, off);
        if (o > v) v = o;
      }
      if (lane == 0) {
        unsigned widx = 0xFFFFFFFFu - (unsigned)(v & 0xFFFFFFFFull);
        const float* pw = P + 3*(size_t)widx;
        float sx = pw[0], sy = pw[1], sz = pw[2];
        cb[0] = sx; cb[1] = sy; cb[2] = sz;
        if (w == 0) {
          float* o = out + ((size_t)b*2048 + 1024 + it) * 3;
          o[0] = sx; o[1] = sy; o[2] = sz;
        }
      }
    }
    __syncthreads();
    cx = cb[0]; cy = cb[1]; cz = cb[2];
  }
}

// ---------------------------------------------------------------- BN+ReLU elementwise (memory-bound)
// act[z][i] = bf16(relu(al[c]*raw[z][i] + be[c])), c = channel of i. uint4 io.
__global__ __launch_bounds__(256) void bn_relu_kernel(
    const u16* __restrict__ raw, u16* __restrict__ act,
    const float* __restrict__ stats,
    const float* __restrict__ gam, const float* __restrict__ bet,
    int C, int chunksPerZ)
{
  int z = blockIdx.y;
  __shared__ float sAl[512];
  __shared__ float sBe[512];
  for (int c = threadIdx.x; c < C; c += 256) {
    float s  = stats[(size_t)z*1024 + c*2];
    float sq = stats[(size_t)z*1024 + c*2 + 1];
    float mean = s * (1.0f/16384.0f);
    float var  = sq * (1.0f/16384.0f) - mean*mean;
    float rs = rsqrtf(var + 1e-5f);
    float al = gam[(size_t)z*C + c] * rs;
    sAl[c] = al;
    sBe[c] = bet[(size_t)z*C + c] - al*mean;
  }
  __syncthreads();
  const u16* rz = raw + (size_t)z * chunksPerZ * 8;
  u16* az = act + (size_t)z * chunksPerZ * 8;
  int cm = C - 1;   // C is a power of two (64/128/512)
  for (int i = blockIdx.x*256 + threadIdx.x; i < chunksPerZ; i += gridDim.x*256) {
    int c0 = (i * 8) & cm;
    uint4 r = *(const uint4*)(rz + (size_t)i*8);
    u16 us[8]; *(uint4*)us = r;
    u16 ot[8];
#pragma unroll
    for (int e = 0; e < 8; e++) {
      float v = sAl[c0+e] * bf2f(us[e]) + sBe[c0+e];
      ot[e] = f2bf(fmaxf(v, 0.0f));
    }
    *(uint4*)(az + (size_t)i*8) = *(uint4*)ot;
  }
}

// ---------------------------------------------------------------- GEMM + fused BN(load, fallback)/stats(epilogue)
__global__ __launch_bounds__(256, 4) void gemm_bn(
    const u16* __restrict__ A, size_t strideA,
    const u16* __restrict__ W, size_t strideW,
    u16* __restrict__ Y, size_t strideY,
    float* __restrict__ statsOut,
    const float* __restrict__ statsIn,
    const float* __restrict__ gam, const float* __restrict__ bet,
    int N, int K, int bnA)
{
  int z = blockIdx.z;
  const u16* Ab = A + (size_t)z * strideA;
  const u16* Wb = W + (size_t)z * strideW;
  u16* Yb = Y + (size_t)z * strideY;
  int m0 = blockIdx.x * 128;
  int n0 = blockIdx.y * 128;

  __shared__ u16 As[128][72];   // +8 pad
  __shared__ u16 Bs[128][72];
  __shared__ float sAl[512];
  __shared__ float sBe[512];

  int tid = threadIdx.x;
  if (bnA) {
    for (int ch = tid; ch < K; ch += 256) {
      float s  = statsIn[(size_t)z*1024 + ch*2];
      float sq = statsIn[(size_t)z*1024 + ch*2 + 1];
      float mean = s * (1.0f/16384.0f);
      float var  = sq * (1.0f/16384.0f) - mean*mean;
      float rs = rsqrtf(var + 1e-5f);
      float al = gam[(size_t)z*K + ch] * rs;
      sAl[ch] = al;
      sBe[ch] = bet[(size_t)z*K + ch] - al*mean;
    }
  }

  f32x4 acc[4][4] = {};
  int lane = tid & 63;
  int wave = tid >> 6;
  int wm = (wave & 1) * 64;
  int wn = (wave >> 1) * 64;
  int lm = lane & 15;
  int lq = lane >> 4;

  for (int k0 = 0; k0 < K; k0 += 64) {
    __syncthreads();
#pragma unroll
    for (int i = 0; i < 4; i++) {
      int f = i*256 + tid;
      int row = f >> 3;
      int kc = (f & 7) * 8;
      uint4 raw = *(const uint4*)(Ab + (size_t)(m0 + row) * K + (k0 + kc));
      if (bnA) {
        u16 us[8]; *(uint4*)us = raw;
        u16 ot[8];
#pragma unroll
        for (int e = 0; e < 8; e++) {
          float v = sAl[k0 + kc + e] * bf2f(us[e]) + sBe[k0 + kc + e];
          ot[e] = f2bf(fmaxf(v, 0.0f));
        }
        *(uint4*)(&As[row][kc]) = *(uint4*)ot;
      } else {
        *(uint4*)(&As[row][kc]) = raw;
      }
    }
#pragma unroll
    for (int i = 0; i < 4; i++) {
      int f = i*256 + tid;
      int row = f >> 3;
      int kc = (f & 7) * 8;
      uint4 v = {0u, 0u, 0u, 0u};
      if (n0 + row < N) v = *(const uint4*)(Wb + (size_t)(n0 + row) * K + (k0 + kc));
      *(uint4*)(&Bs[row][kc]) = v;
    }
    __syncthreads();
#pragma unroll
    for (int kk = 0; kk < 64; kk += 32) {
      bf16x8 af[4], bq[4];
#pragma unroll
      for (int t = 0; t < 4; t++) {
        af[t] = *(const bf16x8*)(&As[wm + t*16 + lm][kk + lq*8]);
        bq[t] = *(const bf16x8*)(&Bs[wn + t*16 + lm][kk + lq*8]);
      }
#pragma unroll
      for (int mt = 0; mt < 4; mt++) {
#pragma unroll
        for (int nt = 0; nt < 4; nt++) {
          acc[mt][nt] = __builtin_amdgcn_mfma_f32_16x16x32_bf16(af[mt], bq[nt], acc[mt][nt], 0, 0, 0);
        }
      }
    }
  }

#pragma unroll
  for (int mt = 0; mt < 4; mt++) {
#pragma unroll
    for (int nt = 0; nt < 4; nt++) {
      int colg = n0 + wn + nt*16 + lm;
      if (colg < N) {
#pragma unroll
        for (int r = 0; r < 4; r++) {
          int rowg = m0 + wm + mt*16 + lq*4 + r;
          Yb[(size_t)rowg * N + colg] = f2bf(acc[mt][nt][r]);
        }
      }
    }
  }
  if (statsOut) {
#pragma unroll
    for (int nt = 0; nt < 4; nt++) {
      float s = 0.f, sq = 0.f;
#pragma unroll
      for (int mt = 0; mt < 4; mt++) {
#pragma unroll
        for (int r = 0; r < 4; r++) { float v = acc[mt][nt][r]; s += v; sq += v*v; }
      }
      s  += __shfl_xor(s, 16);  s  += __shfl_xor(s, 32);
      sq += __shfl_xor(sq, 16); sq += __shfl_xor(sq, 32);
      int colg = n0 + wn + nt*16 + lm;
      if (lq == 0 && colg < N) {
        atomicAdd(&statsOut[(size_t)z*1024 + colg*2],     s);
        atomicAdd(&statsOut[(size_t)z*1024 + colg*2 + 1], sq);
      }
    }
  }
}

// ---------------------------------------------------------------- finale: softmax + pts + 3x64 proj
__global__ __launch_bounds__(256, 1) void finale_kernel(
    const u16* __restrict__ h4,       // [8][16384][64] pre-BN bf16
    const u16* __restrict__ t3,       // [8][16384][128] logits bf16
    const float* __restrict__ stats4,
    const float* __restrict__ mg4, const float* __restrict__ mB4,
    const float* __restrict__ aW4, const float* __restrict__ ab4,
    float* __restrict__ out)
{
  int b = blockIdx.x, g = blockIdx.y;
  int tid = threadIdx.x;
  __shared__ u16 base_s[512*64];
  __shared__ u16 wbuf[512*64];
  __shared__ float ptsb[64*64];
  __shared__ float2 abl[64];
  __shared__ float red[4*64];
  __shared__ float colmax[64];
  __shared__ float colinv[64];

  if (tid < 64) {
    float s  = stats4[(size_t)g*1024 + tid*2];
    float sq = stats4[(size_t)g*1024 + tid*2 + 1];
    float mean = s * (1.0f/16384.0f);
    float var  = sq * (1.0f/16384.0f) - mean*mean;
    float rs = rsqrtf(var + 1e-5f);
    float al = mg4[g*64 + tid] * rs;
    abl[tid] = make_float2(al, mB4[g*64 + tid] - al*mean);
  }
  __syncthreads();

  const u16* h4b = h4 + ((size_t)g*MROWS + b*LSEQ) * 64;
  for (int i = 0; i < 16; i++) {
    int u = i*256 + tid;
    int l = u >> 3;
    int kc = (u & 7) * 8;
    uint4 raw = *(const uint4*)(h4b + (size_t)l*64 + kc);
    u16 us[8]; *(uint4*)us = raw;
    u16 ot[8];
#pragma unroll
    for (int e = 0; e < 8; e++) {
      float2 p = abl[kc + e];
      float v = p.x * bf2f(us[e]) + p.y;
      ot[e] = f2bf(fmaxf(v, 0.0f));
    }
    *(uint4*)(&base_s[l*64 + kc]) = *(uint4*)ot;
  }

  int col = tid & 63;
  int ts  = tid >> 6;
  int mch0 = (tid & 31) * 2;
  int k0 = (tid >> 5) * 8;

  for (int half = 0; half < 2; half++) {
    __syncthreads();
    const u16* t3b = t3 + ((size_t)g*MROWS + b*LSEQ) * 128 + half*64;
    for (int i = 0; i < 16; i++) {
      int u = i*256 + tid;
      int l = u >> 3;
      int kc = (u & 7) * 8;
      *(uint4*)(&wbuf[l*64 + kc]) = *(const uint4*)(t3b + (size_t)l*128 + kc);
    }
    __syncthreads();
    float mx = -1e30f;
    for (int j = 0; j < 128; j++) {
      int l = ts + j*4;
      mx = fmaxf(mx, bf2f(wbuf[l*64 + col]));
    }
    red[ts*64 + col] = mx;
    __syncthreads();
    if (ts == 0)
      colmax[col] = fmaxf(fmaxf(red[col], red[64+col]), fmaxf(red[128+col], red[192+col]));
    __syncthreads();
    mx = colmax[col];
    float sm = 0.0f;
    for (int j = 0; j < 128; j++) {
      int l = ts + j*4;
      float e = __expf(bf2f(wbuf[l*64 + col]) - mx);
      sm += e;
      wbuf[l*64 + col] = f2bf(e);
    }
    red[ts*64 + col] = sm;
    __syncthreads();
    if (ts == 0)
      colinv[col] = 1.0f / (red[col] + red[64+col] + red[128+col] + red[192+col]);
    __syncthreads();

    float a0[8] = {}, a1[8] = {};
    for (int l = 0; l < 512; l++) {
      unsigned wvv = *(const unsigned*)(&wbuf[l*64 + mch0]);
      float w0 = __uint_as_float((wvv & 0xffffu) << 16);
      float w1 = __uint_as_float((wvv >> 16) << 16);
      u16 bs[8]; *(uint4*)bs = *(const uint4*)(&base_s[l*64 + k0]);
#pragma unroll
      for (int e = 0; e < 8; e++) {
        float bv = bf2f(bs[e]);
        a0[e] = fmaf(w0, bv, a0[e]);
        a1[e] = fmaf(w1, bv, a1[e]);
      }
    }
    float i0 = colinv[mch0], i1 = colinv[mch0 + 1];
#pragma unroll
    for (int e = 0; e < 8; e++) {
      ptsb[mch0*64 + k0 + e]       = a0[e] * i0;
      ptsb[(mch0+1)*64 + k0 + e]   = a1[e] * i1;
    }
    __syncthreads();
    if (tid < 64) {
      const float* w4 = aW4 + (size_t)g*192;
      float o0 = ab4[g*3], o1 = ab4[g*3+1], o2 = ab4[g*3+2];
      for (int k = 0; k < 64; k++) {
        float pv = ptsb[tid*64 + k];
        o0 = fmaf(w4[k],      pv, o0);
        o1 = fmaf(w4[64 + k], pv, o1);
        o2 = fmaf(w4[128 + k],pv, o2);
      }
      float* op = out + ((size_t)b*2048 + g*128 + half*64 + tid) * 3;
      op[0] = o0; op[1] = o1; op[2] = o2;
    }
  }
}

// ---------------------------------------------------------------- host
extern "C" void kernel_launch(void* const* d_in, const int* in_sizes, int n_in,
                              void* d_out, int out_size, void* d_ws, size_t ws_size,
                              hipStream_t stream)
{
  (void)in_sizes; (void)n_in; (void)out_size;
  const float* x    = (const float*)d_in[0];
  const float* xprt = (const float*)d_in[1];
  const float* mW1 = (const float*)d_in[2];
  const float* mg1 = (const float*)d_in[4];
  const float* mB1 = (const float*)d_in[5];
  const float* mW2 = (const float*)d_in[6];
  const float* mg2 = (const float*)d_in[8];
  const float* mB2 = (const float*)d_in[9];
  const float* mW3 = (const float*)d_in[10];
  const float* mg3 = (const float*)d_in[12];
  const float* mB3 = (const float*)d_in[13];
  const float* mW4 = (const float*)d_in[14];
  const float* mg4 = (const float*)d_in[16];
  const float* mB4 = (const float*)d_in[17];
  const float* aW1 = (const float*)d_in[18];
  const float* ag1 = (const float*)d_in[20];
  const float* aB1 = (const float*)d_in[21];
  const float* aW2 = (const float*)d_in[22];
  const float* ag2 = (const float*)d_in[24];
  const float* aB2 = (const float*)d_in[25];
  const float* aW3 = (const float*)d_in[26];
  const float* aW4 = (const float*)d_in[28];
  const float* ab4 = (const float*)d_in[29];
  float* out = (float*)d_out;

  char* ws = (char*)d_ws;
  size_t off = 0;
  auto carve = [&](size_t bytes) -> char* {
    char* p = ws + off;
    off += (bytes + 255) & ~(size_t)255;
    return p;
  };
  // common small buffers
  u16* xb   = (u16*)carve((size_t)MROWS*256*2);
  u16* w1b  = (u16*)carve((size_t)NBR*512*256*2);
  u16* w2b  = (u16*)carve((size_t)NBR*512*512*2);
  u16* w3b  = (u16*)carve((size_t)NBR*512*512*2);
  u16* w4b  = (u16*)carve((size_t)NBR*64*512*2);
  u16* aw1b = (u16*)carve((size_t)NBR*64*64*2);
  u16* aw2b = (u16*)carve((size_t)NBR*128*64*2);
  u16* aw3b = (u16*)carve((size_t)NBR*128*128*2);
  float* stats = (float*)carve((size_t)6*NBR*1024*4);
  u64* slots = (u64*)carve((size_t)BATCH*8192*8);
  size_t commonOff = off;

  // preferred (z=8) layout needs 2x128MB ping-pong + 2x16MB h4
  size_t bigNeed = commonOff + 2*((size_t)NBR*MROWS*512*2 + 256) + 2*((size_t)NBR*MROWS*64*2 + 256);
  bool bigPath = (ws_size >= bigNeed);

  cvt_kernel<<<1024, 256, 0, stream>>>(x,   xb,   MROWS*256);
  cvt_kernel<<<1024, 256, 0, stream>>>(mW1, w1b,  NBR*512*256);
  cvt_kernel<<<1024, 256, 0, stream>>>(mW2, w2b,  NBR*512*512);
  cvt_kernel<<<1024, 256, 0, stream>>>(mW3, w3b,  NBR*512*512);
  cvt_kernel<<<1024, 256, 0, stream>>>(mW4, w4b,  NBR*64*512);
  cvt_kernel<<<256,  256, 0, stream>>>(aW1, aw1b, NBR*64*64);
  cvt_kernel<<<256,  256, 0, stream>>>(aW2, aw2b, NBR*128*64);
  cvt_kernel<<<256,  256, 0, stream>>>(aW3, aw3b, NBR*128*128);
  hipMemsetAsync(stats, 0, (size_t)6*NBR*1024*4, stream);
  hipMemsetAsync(slots, 0, (size_t)BATCH*8192*8, stream);

  fps_kernel<<<dim3(8, BATCH), 1024, 0, stream>>>(xprt, out, slots);

  if (bigPath) {
    u16* hR  = (u16*)carve((size_t)NBR*MROWS*512*2);   // raw ping (also t1r/t2r)
    u16* hA  = (u16*)carve((size_t)NBR*MROWS*512*2);   // act pong (also t1a/t2a/t3)
    u16* h4  = (u16*)carve((size_t)NBR*MROWS*64*2);    // raw L4 (finale input)
    u16* h4a = (u16*)carve((size_t)NBR*MROWS*64*2);    // act L4
    u16* t1r = hR;
    u16* t1a = hA;
    u16* t2r = hR + (size_t)NBR*MROWS*128;             // offset in elements: 32MB
    u16* t2a = hA + (size_t)NBR*MROWS*128;
    u16* t3  = hA + (size_t)2*NBR*MROWS*128;           // 64MB offset

    const int bigChunks = MROWS*512/8, smChunks = MROWS*64/8, mdChunks = MROWS*128/8;

    // L1: hR = x @ W1^T (raw), stats0
    gemm_bn<<<dim3(128,4,8), 256, 0, stream>>>(
      xb, (size_t)0, w1b, (size_t)512*256, hR, (size_t)MROWS*512,
      stats + 0*NBR*1024, nullptr, nullptr, nullptr, 512, 256, 0);
    bn_relu_kernel<<<dim3(1024,8), 256, 0, stream>>>(hR, hA, stats + 0*NBR*1024, mg1, mB1, 512, bigChunks);
    // L2
    gemm_bn<<<dim3(128,4,8), 256, 0, stream>>>(
      hA, (size_t)MROWS*512, w2b, (size_t)512*512, hR, (size_t)MROWS*512,
      stats + 1*NBR*1024, nullptr, nullptr, nullptr, 512, 512, 0);
    bn_relu_kernel<<<dim3(1024,8), 256, 0, stream>>>(hR, hA, stats + 1*NBR*1024, mg2, mB2, 512, bigChunks);
    // L3
    gemm_bn<<<dim3(128,4,8), 256, 0, stream>>>(
      hA, (size_t)MROWS*512, w3b, (size_t)512*512, hR, (size_t)MROWS*512,
      stats + 2*NBR*1024, nullptr, nullptr, nullptr, 512, 512, 0);
    bn_relu_kernel<<<dim3(1024,8), 256, 0, stream>>>(hR, hA, stats + 2*NBR*1024, mg3, mB3, 512, bigChunks);
    // L4 -> h4 raw (finale uses raw + stats3)
    gemm_bn<<<dim3(128,1,8), 256, 0, stream>>>(
      hA, (size_t)MROWS*512, w4b, (size_t)64*512, h4, (size_t)MROWS*64,
      stats + 3*NBR*1024, nullptr, nullptr, nullptr, 64, 512, 0);
    bn_relu_kernel<<<dim3(256,8), 256, 0, stream>>>(h4, h4a, stats + 3*NBR*1024, mg4, mB4, 64, smChunks);
    // t1
    gemm_bn<<<dim3(128,1,8), 256, 0, stream>>>(
      h4a, (size_t)MROWS*64, aw1b, (size_t)64*64, t1r, (size_t)MROWS*64,
      stats + 4*NBR*1024, nullptr, nullptr, nullptr, 64, 64, 0);
    bn_relu_kernel<<<dim3(256,8), 256, 0, stream>>>(t1r, t1a, stats + 4*NBR*1024, ag1, aB1, 64, smChunks);
    // t2
    gemm_bn<<<dim3(128,1,8), 256, 0, stream>>>(
      t1a, (size_t)MROWS*64, aw2b, (size_t)128*64, t2r, (size_t)MROWS*128,
      stats + 5*NBR*1024, nullptr, nullptr, nullptr, 128, 64, 0);
    bn_relu_kernel<<<dim3(512,8), 256, 0, stream>>>(t2r, t2a, stats + 5*NBR*1024, ag2, aB2, 128, mdChunks);
    // t3 (no stats; ab3 softmax-invariant)
    gemm_bn<<<dim3(128,1,8), 256, 0, stream>>>(
      t2a, (size_t)MROWS*128, aw3b, (size_t)128*128, t3, (size_t)MROWS*128,
      nullptr, nullptr, nullptr, nullptr, 128, 128, 0);

    finale_kernel<<<dim3(32,8), 256, 0, stream>>>(
      h4, t3, stats + 3*NBR*1024, mg4, mB4, aW4, ab4, out);
  } else {
    // fallback: R6 fused-BN z=2 path (~117MB)
    u16* hA = (u16*)carve((size_t)2*MROWS*512*2);
    u16* hB = (u16*)carve((size_t)2*MROWS*512*2);
    u16* h4 = (u16*)carve((size_t)NBR*MROWS*64*2);
    u16* t1 = (u16*)carve((size_t)NBR*MROWS*64*2);
    u16* t2 = hB;
    u16* t3 = hA;

    for (int p = 0; p < 4; p++) {
      size_t g0 = (size_t)p * 2;
      gemm_bn<<<dim3(128,4,2), 256, 0, stream>>>(
        xb, (size_t)0, w1b + g0*512*256, (size_t)512*256, hA, (size_t)MROWS*512,
        stats + 0*NBR*1024 + g0*1024, nullptr, nullptr, nullptr, 512, 256, 0);
      gemm_bn<<<dim3(128,4,2), 256, 0, stream>>>(
        hA, (size_t)MROWS*512, w2b + g0*512*512, (size_t)512*512, hB, (size_t)MROWS*512,
        stats + 1*NBR*1024 + g0*1024,
        stats + 0*NBR*1024 + g0*1024, mg1 + g0*512, mB1 + g0*512, 512, 512, 1);
      gemm_bn<<<dim3(128,4,2), 256, 0, stream>>>(
        hB, (size_t)MROWS*512, w3b + g0*512*512, (size_t)512*512, hA, (size_t)MROWS*512,
        stats + 2*NBR*1024 + g0*1024,
        stats + 1*NBR*1024 + g0*1024, mg2 + g0*512, mB2 + g0*512, 512, 512, 1);
      gemm_bn<<<dim3(128,1,2), 256, 0, stream>>>(
        hA, (size_t)MROWS*512, w4b + g0*64*512, (size_t)64*512,
        h4 + g0*MROWS*64, (size_t)MROWS*64,
        stats + 3*NBR*1024 + g0*1024,
        stats + 2*NBR*1024 + g0*1024, mg3 + g0*512, mB3 + g0*512, 64, 512, 1);
    }
    gemm_bn<<<dim3(128,1,8), 256, 0, stream>>>(
      h4, (size_t)MROWS*64, aw1b, (size_t)64*64, t1, (size_t)MROWS*64,
      stats + 4*NBR*1024, stats + 3*NBR*1024, mg4, mB4, 64, 64, 1);
    gemm_bn<<<dim3(128,1,8), 256, 0, stream>>>(
      t1, (size_t)MROWS*64, aw2b, (size_t)128*64, t2, (size_t)MROWS*128,
      stats + 5*NBR*1024, stats + 4*NBR*1024, ag1, aB1, 128, 64, 1);
    gemm_bn<<<dim3(128,1,8), 256, 0, stream>>>(
      t2, (size_t)MROWS*128, aw3b, (size_t)128*128, t3, (size_t)MROWS*128,
      nullptr, stats + 5*NBR*1024, ag2, aB2, 128, 128, 1);

    finale_kernel<<<dim3(32,8), 256, 0, stream>>>(
      h4, t3, stats + 3*NBR*1024, mg4, mB4, aW4, ab4, out);
  }
}